// Round 3
// baseline (448.853 us; speedup 1.0000x reference)
//
#include <hip/hip_runtime.h>
#include <math.h>

#define Bn 8192
#define Sn 200
#define Fn 128
#define En 64
#define An 64
#define H1n 128
#define H2n 64
#define H3n 32
#define EPSn 1e-5f
#define CH 16   // chunk rows per wave-iteration

typedef __attribute__((ext_vector_type(8))) short bf16x8;
typedef __attribute__((ext_vector_type(4))) float f32x4;

__device__ __forceinline__ uint pack_bf2(float a, float b) {
    uint ua = __float_as_uint(a), ub = __float_as_uint(b);
    ua += 0x7fffu + ((ua >> 16) & 1u);
    ub += 0x7fffu + ((ub >> 16) & 1u);
    return (ua >> 16) | (ub & 0xffff0000u);
}

// ---------- prep: pack Wik = Wi@Wk into per-lane B-fragment order (bf16),
// ---------- plus bk = bi@Wk (fp32). idx = ((ct*4+k)*64 + lane)*8 + j
__global__ void din_prep(const float* __restrict__ Wi, const float* __restrict__ bi,
                         const float* __restrict__ Wk,
                         ushort* __restrict__ wikp, float* __restrict__ bk) {
    int idx = blockIdx.x * blockDim.x + threadIdx.x;   // 0..8191
    int j = idx & 7, l = (idx >> 3) & 63, ctk = idx >> 9;
    int ct = ctk >> 2, k = ctk & 3;
    int kk = k * 32 + 8 * (l >> 4) + j;   // f index (row of Wik)
    int aa = ct * 16 + (l & 15);          // a index (col of Wik)
    float s = 0.f;
    for (int e = 0; e < En; ++e) s = fmaf(Wi[kk * En + e], Wk[e * An + aa], s);
    uint us = __float_as_uint(s); us += 0x7fffu + ((us >> 16) & 1u);
    wikp[idx] = (ushort)(us >> 16);
    if (idx < An) {
        float t = 0.f;
        for (int e = 0; e < En; ++e) t = fmaf(bi[e], Wk[e * An + idx], t);
        bk[idx] = t;
    }
}

// ---------- main: one WAVE per batch row; 4 waves/block; no barriers in loop
__global__ __launch_bounds__(256, 4) void din_main(
    const float* __restrict__ cand, const float* __restrict__ hist,
    const int* __restrict__ hlen,
    const float* __restrict__ Wi, const float* __restrict__ bi,
    const float* __restrict__ Wq, const float* __restrict__ Wv,
    const ushort* __restrict__ wikp, const float* __restrict__ bk,
    const float* __restrict__ W1, const float* __restrict__ b1,
    const float* __restrict__ g1, const float* __restrict__ be1,
    const float* __restrict__ m1, const float* __restrict__ v1,
    const float* __restrict__ W2, const float* __restrict__ b2,
    const float* __restrict__ g2, const float* __restrict__ be2,
    const float* __restrict__ m2, const float* __restrict__ v2,
    const float* __restrict__ W3, const float* __restrict__ b3,
    const float* __restrict__ g3, const float* __restrict__ be3,
    const float* __restrict__ m3, const float* __restrict__ v3,
    const float* __restrict__ Wo, const float* __restrict__ bo,
    float* __restrict__ out)
{
    const int tid = threadIdx.x;
    const int wv = tid >> 6;
    const int lane = tid & 63;
    const int b = blockIdx.x * 4 + wv;

    __shared__ uint wik_l[4096];                     // 16KB shared B frags (swizzled)
    __shared__ alignas(16) uint h_u[4][CH * 64];     // 4KB per wave, bf16x2/dword, swizzled
    __shared__ alignas(16) float w_sc[4][16];        // per-wave chunk scores
    __shared__ float s_ce[4][64];                    // per-wave scratch

    // ---- block-coop: stage packed Wik -> LDS (swizzled) ----
    {
        const uint4* wp = (const uint4*)wikp;        // 1024 uint4
        for (int q = tid; q < 1024; q += 256) {
            uint4 v = wp[q];
            int l = q & 63;
            int dw = (q * 4) ^ (((l >> 3) & 3) << 2);
            *(uint4*)&wik_l[dw] = v;
        }
    }
    __syncthreads();   // only barrier; waves independent after this

    const int len = hlen[b];
    const float* hb = hist + (size_t)b * Sn * Fn;
    uint* hw = h_u[wv];

    // ---- issue prefetch of chunk 0 (8 float4/lane, coalesced) ----
    // lane's rows: sl = 2*i + (lane>>5), f4 = lane&31 (fixed per lane)
    const int f4l = lane & 31;
    const int rhalf = lane >> 5;
    float4 pv[8];
    #pragma unroll
    for (int i = 0; i < 8; ++i) {
        int sl = 2 * i + rhalf;
        pv[i] = (sl < len) ? ((const float4*)(hb + (size_t)sl * Fn))[f4l]
                           : make_float4(0.f, 0.f, 0.f, 0.f);
    }

    // ---- prologue under the prefetch: ce = cand@Wi + bi (lane = e) ----
    {
        const float* cr = cand + (size_t)b * Fn;
        float a0 = 0.f, a1 = 0.f, a2 = 0.f, a3 = 0.f;
        #pragma unroll
        for (int f = 0; f < Fn; f += 4) {
            a0 = fmaf(cr[f + 0], Wi[(f + 0) * En + lane], a0);
            a1 = fmaf(cr[f + 1], Wi[(f + 1) * En + lane], a1);
            a2 = fmaf(cr[f + 2], Wi[(f + 2) * En + lane], a2);
            a3 = fmaf(cr[f + 3], Wi[(f + 3) * En + lane], a3);
        }
        s_ce[wv][lane] = (a0 + a1) + (a2 + a3) + bi[lane];
    }
    const float ce = s_ce[wv][lane];
    // qhb = ce@Wq + bk (lane = a)
    float qh;
    {
        float a0 = 0.f, a1 = 0.f;
        #pragma unroll
        for (int e = 0; e < En; e += 2) {
            a0 = fmaf(s_ce[wv][e + 0], Wq[(e + 0) * An + lane], a0);
            a1 = fmaf(s_ce[wv][e + 1], Wq[(e + 1) * An + lane], a1);
        }
        qh = a0 + a1 + bk[lane];
    }
    s_ce[wv][lane] = qh;   // redistribute
    float qhb_l[4], wv_l[4];
    #pragma unroll
    for (int ct = 0; ct < 4; ++ct) {
        qhb_l[ct] = s_ce[wv][ct * 16 + (lane & 15)];
        wv_l[ct]  = Wv[ct * 16 + (lane & 15)];
    }

    float m = -3.0e38f, d = 0.f;
    float2 acc2 = make_float2(0.f, 0.f), sum2 = make_float2(0.f, 0.f);
    const int nch = (len + CH - 1) >> 4;

    for (int c = 0; c < nch; ++c) {
        const int sc0 = c * CH;
        // ---- write prefetched regs -> LDS (waits vmcnt implicitly) ----
        #pragma unroll
        for (int i = 0; i < 8; ++i) {
            int sl = 2 * i + rhalf;
            uint2 pw;
            pw.x = pack_bf2(pv[i].x, pv[i].y);
            pw.y = pack_bf2(pv[i].z, pv[i].w);
            int dw = (2 * f4l) ^ ((sl & 7) << 2);
            *(uint2*)&hw[sl * 64 + dw] = pw;
        }
        // ---- issue prefetch for chunk c+1 ----
        if (c + 1 < nch) {
            const int nb = sc0 + CH;
            #pragma unroll
            for (int i = 0; i < 8; ++i) {
                int sg = nb + 2 * i + rhalf;
                pv[i] = (sg < len) ? ((const float4*)(hb + (size_t)sg * Fn))[f4l]
                                   : make_float4(0.f, 0.f, 0.f, 0.f);
            }
        }
        // ---- scores via MFMA (16 rows x 64 a) ----
        {
            const int r = lane & 15;
            bf16x8 afr[4];
            #pragma unroll
            for (int k = 0; k < 4; ++k) {
                int dwA = (k * 16 + 4 * (lane >> 4)) ^ ((r & 7) << 2);
                afr[k] = *(const bf16x8*)&hw[r * 64 + dwA];
            }
            float contrib[4] = {0.f, 0.f, 0.f, 0.f};
            #pragma unroll
            for (int ct = 0; ct < 4; ++ct) {
                f32x4 acc = {0.f, 0.f, 0.f, 0.f};
                #pragma unroll
                for (int k = 0; k < 4; ++k) {
                    int dwB = (((ct * 4 + k) * 64 + lane) * 4) ^ (((lane >> 3) & 3) << 2);
                    bf16x8 bfr = *(const bf16x8*)&wik_l[dwB];
                    acc = __builtin_amdgcn_mfma_f32_16x16x32_bf16(afr[k], bfr, acc, 0, 0, 0);
                }
                float qv = qhb_l[ct], wvv = wv_l[ct];
                #pragma unroll
                for (int rr = 0; rr < 4; ++rr)
                    contrib[rr] += fmaxf(acc[rr] + qv, 0.f) * wvv;
            }
            #pragma unroll
            for (int o = 1; o < 16; o <<= 1) {
                #pragma unroll
                for (int rr = 0; rr < 4; ++rr)
                    contrib[rr] += __shfl_xor(contrib[rr], o, 64);
            }
            if ((lane & 15) == 0) {
                #pragma unroll
                for (int rr = 0; rr < 4; ++rr) {
                    int j = (lane >> 4) * 4 + rr;
                    w_sc[wv][j] = (sc0 + j < len) ? contrib[rr] : -1e30f;
                }
            }
        }
        // ---- redundant all-lane online softmax over 16 scores ----
        const f32x4* wsp = (const f32x4*)w_sc[wv];
        f32x4 s0 = wsp[0], s1 = wsp[1], s2 = wsp[2], s3 = wsp[3];
        float mloc = fmaxf(
            fmaxf(fmaxf(fmaxf(s0[0], s0[1]), fmaxf(s0[2], s0[3])),
                  fmaxf(fmaxf(s1[0], s1[1]), fmaxf(s1[2], s1[3]))),
            fmaxf(fmaxf(fmaxf(s2[0], s2[1]), fmaxf(s2[2], s2[3])),
                  fmaxf(fmaxf(s3[0], s3[1]), fmaxf(s3[2], s3[3]))));
        float mn = fmaxf(m, mloc);
        float cc = __expf(m - mn);
        m = mn;
        float wj[16];
        #pragma unroll
        for (int j = 0; j < 4; ++j) {
            wj[j]      = __expf(s0[j] - mn);
            wj[4 + j]  = __expf(s1[j] - mn);
            wj[8 + j]  = __expf(s2[j] - mn);
            wj[12 + j] = __expf(s3[j] - mn);
        }
        float dsum = 0.f;
        #pragma unroll
        for (int j = 0; j < 16; ++j) dsum += wj[j];
        d = d * cc + dsum;
        // ---- pooling (guard-free: invalid rows have w=0 and h=0) ----
        acc2.x *= cc; acc2.y *= cc;
        #pragma unroll
        for (int j = 0; j < CH; ++j) {
            uint hv = hw[j * 64 + (lane ^ ((j & 7) << 2))];
            float hx = __uint_as_float(hv << 16);
            float hy = __uint_as_float(hv & 0xffff0000u);
            acc2.x = fmaf(wj[j], hx, acc2.x);
            acc2.y = fmaf(wj[j], hy, acc2.y);
            sum2.x += hx; sum2.y += hy;
        }
    }

    // ---- per-wave epilogue: reuse this wave's h region as fp32 scratch ----
    float* fb = (float*)hw;   // [0:128) if_f, [128:256) av_f, [256:448) x, [448:576) h1, [576:640) h2
    const float invd = 1.f / d;
    const float invl = 1.f / (float)len;
    fb[2 * lane + 0] = acc2.x * invd;
    fb[2 * lane + 1] = acc2.y * invd;
    fb[128 + 2 * lane + 0] = sum2.x * invl;
    fb[128 + 2 * lane + 1] = sum2.y * invl;

    // project interest_f/avg_f through Wi (+bi); lane = e
    float xq = bi[lane], xa = xq;
    #pragma unroll 8
    for (int f = 0; f < Fn; ++f) {
        float w = Wi[f * En + lane];
        xq = fmaf(fb[f], w, xq);
        xa = fmaf(fb[128 + f], w, xa);
    }
    fb[256 + lane] = xq;
    fb[256 + 64 + lane] = ce;
    fb[256 + 128 + lane] = xa;

    // MLP layer 1 (192 -> 128): lane does o and o+64
    {
        float a0 = b1[lane], a1 = b1[lane + 64];
        #pragma unroll 8
        for (int j = 0; j < 3 * En; ++j) {
            float xv = fb[256 + j];
            a0 = fmaf(xv, W1[j * H1n + lane], a0);
            a1 = fmaf(xv, W1[j * H1n + lane + 64], a1);
        }
        float h0 = fmaxf((a0 - m1[lane]) * rsqrtf(v1[lane] + EPSn) * g1[lane] + be1[lane], 0.f);
        float h1v = fmaxf((a1 - m1[lane + 64]) * rsqrtf(v1[lane + 64] + EPSn) * g1[lane + 64] + be1[lane + 64], 0.f);
        fb[448 + lane] = h0;
        fb[448 + lane + 64] = h1v;
    }
    // layer 2 (128 -> 64): lane = o
    {
        float a0 = b2[lane];
        #pragma unroll 8
        for (int j = 0; j < H1n; ++j)
            a0 = fmaf(fb[448 + j], W2[j * H2n + lane], a0);
        fb[576 + lane] = fmaxf((a0 - m2[lane]) * rsqrtf(v2[lane] + EPSn) * g2[lane] + be2[lane], 0.f);
    }
    // layer 3 (64 -> 32) + Wo, lanes < 32
    float p = 0.f;
    if (lane < H3n) {
        float a0 = b3[lane];
        #pragma unroll 8
        for (int j = 0; j < H2n; ++j)
            a0 = fmaf(fb[576 + j], W3[j * H3n + lane], a0);
        float h3 = fmaxf((a0 - m3[lane]) * rsqrtf(v3[lane] + EPSn) * g3[lane] + be3[lane], 0.f);
        p = h3 * Wo[lane];
    }
    #pragma unroll
    for (int o = 1; o < 64; o <<= 1) p += __shfl_xor(p, o, 64);
    if (lane == 0) out[b] = 1.f / (1.f + __expf(-(p + bo[0])));
}

extern "C" void kernel_launch(void* const* d_in, const int* in_sizes, int n_in,
                              void* d_out, int out_size, void* d_ws, size_t ws_size,
                              hipStream_t stream) {
    const float* cand = (const float*)d_in[0];
    const float* hist = (const float*)d_in[1];
    const int*   hlen = (const int*)d_in[2];
    const float* Wi = (const float*)d_in[3];
    const float* bi = (const float*)d_in[4];
    const float* Wq = (const float*)d_in[5];
    const float* Wk = (const float*)d_in[6];
    const float* Wv = (const float*)d_in[7];
    const float* W1 = (const float*)d_in[8];
    const float* b1 = (const float*)d_in[9];
    const float* g1 = (const float*)d_in[10];
    const float* be1 = (const float*)d_in[11];
    const float* m1 = (const float*)d_in[12];
    const float* v1 = (const float*)d_in[13];
    const float* W2 = (const float*)d_in[14];
    const float* b2 = (const float*)d_in[15];
    const float* g2 = (const float*)d_in[16];
    const float* be2 = (const float*)d_in[17];
    const float* m2 = (const float*)d_in[18];
    const float* v2 = (const float*)d_in[19];
    const float* W3 = (const float*)d_in[20];
    const float* b3 = (const float*)d_in[21];
    const float* g3 = (const float*)d_in[22];
    const float* be3 = (const float*)d_in[23];
    const float* m3 = (const float*)d_in[24];
    const float* v3 = (const float*)d_in[25];
    const float* Wo = (const float*)d_in[26];
    const float* bo = (const float*)d_in[27];
    float* out = (float*)d_out;

    ushort* wikp = (ushort*)d_ws;                 // 8192 ushorts = 16KB
    float*  bk   = (float*)((char*)d_ws + 16384); // 64 floats

    din_prep<<<32, 256, 0, stream>>>(Wi, bi, Wk, wikp, bk);
    din_main<<<Bn / 4, 256, 0, stream>>>(cand, hist, hlen, Wi, bi, Wq, Wv, wikp, bk,
                                         W1, b1, g1, be1, m1, v1,
                                         W2, b2, g2, be2, m2, v2,
                                         W3, b3, g3, be3, m3, v3,
                                         Wo, bo, out);
}